// Round 2
// baseline (445.489 us; speedup 1.0000x reference)
//
#include <hip/hip_runtime.h>
#include <stdint.h>

// GaussianTrans: out[b,r,c,d] = sum_h sig(disX[c,h]+attX[b,r,c,h]) * V[b,r,h,d]
//                             + sum_w sig(disY[r,w]+attY[b,c,r,w]) * V[b,w,c,d]
// B=16, H=W=64, D=512. ALL I/O IS FP32 (per reference). MFMA in bf16 with
// fp32 accumulation; bf16 rounding error ~0.05 vs 0.21 threshold.

typedef __attribute__((ext_vector_type(8))) __bf16 bf16x8;
typedef __attribute__((ext_vector_type(8))) short short8;
typedef __attribute__((ext_vector_type(4))) float f32x4;

union U8 { short8 s; bf16x8 b; unsigned short u[8]; };

__device__ __forceinline__ unsigned short f2bf(float f) {
    union { float f; unsigned int i; } v; v.f = f;
    return (unsigned short)((v.i + 0x7fffu + ((v.i >> 16) & 1u)) >> 16);  // RNE
}
__device__ __forceinline__ float fsigmoid(float x) {
    float e = __builtin_amdgcn_exp2f(-1.44269504f * x);   // exp(-x)
    return __builtin_amdgcn_rcpf(1.0f + e);
}

// One (b, i) GEMM: M=64 (m), N=256 (d half), K=64 (k).
//   A[m][k] = sigmoid(-(shift*(k-m)^2 + bias) + att[(b*64+i)*4096 + m*64 + k])
//   B[k][d] = V[b*2097152 + i*S_I + k*S_K + d]
//   out at   b*2097152 + i*S_I + m*S_K + d     (ACCUM: read-add-write)
// X-pass: i=r, S_I=32768, S_K=512.  Y-pass: i=c, S_I=512, S_K=32768.
template <int S_I, int S_K, bool ACCUM>
__global__ __launch_bounds__(256)
void gauss_gemm(const float* __restrict__ att,
                const float* __restrict__ V,
                float* __restrict__ out,
                const float* __restrict__ shiftp,
                const float* __restrict__ biasp) {
    __shared__ unsigned short S[4096];  // sigmoid(A) as bf16, fragment order [q][m][j]

    const int bid   = blockIdx.x;
    const int dhalf = bid & 1;
    const int i     = (bid >> 1) & 63;
    const int b     = bid >> 7;
    const int t     = threadIdx.x;

    const float shift = shiftp[0];
    const float bias  = biasp[0];

    // ---- stage sigmoid(dis + att) into LDS as bf16, fragment-ready layout ----
    const float* ab = att + (size_t)(b * 64 + i) * 4096;  // [m][k]
#pragma unroll
    for (int chunk = 0; chunk < 2; ++chunk) {
        int flat = t + chunk * 256;          // 0..511 over [q(8)][m(64)]
        int q = flat >> 6, m = flat & 63;
        const float* ap = ab + m * 64 + q * 8;
        f32x4 av0 = *(const f32x4*)(ap);
        f32x4 av1 = *(const f32x4*)(ap + 4);
        U8 res;
#pragma unroll
        for (int j = 0; j < 8; ++j) {
            float a    = (j < 4) ? av0[j & 3] : av1[j & 3];
            float diff = (float)(q * 8 + j - m);            // (k - m)
            float dis  = -(shift * diff * diff + bias);
            res.u[j]   = f2bf(fsigmoid(dis + a));
        }
        *(short8*)(&S[flat * 8]) = res.s;
    }
    __syncthreads();

    const int lane = t & 63, wid = t >> 6;
    const int l15 = lane & 15, quad = lane >> 4;
    const int dbase = dhalf * 256 + wid * 64;   // each wave owns a 64-wide d slice

    const size_t base = (size_t)b * 2097152 + (size_t)i * S_I;
    const float* vb = V + base;

    f32x4 acc[4][4];
#pragma unroll
    for (int mt = 0; mt < 4; ++mt)
#pragma unroll
        for (int nt = 0; nt < 4; ++nt) acc[mt][nt] = (f32x4)0.0f;

#pragma unroll
    for (int ks = 0; ks < 2; ++ks) {
        bf16x8 af[4];
#pragma unroll
        for (int mt = 0; mt < 4; ++mt) {
            U8 a;
            a.s = *(const short8*)(&S[((ks * 4 + quad) * 64 + mt * 16 + l15) * 8]);
            af[mt] = a.b;
        }
#pragma unroll
        for (int nt = 0; nt < 4; ++nt) {
            const int d = dbase + nt * 16 + l15;
            const float* vp = vb + (size_t)(ks * 32 + quad * 8) * S_K + d;
            U8 bvec;
#pragma unroll
            for (int j = 0; j < 8; ++j) bvec.u[j] = f2bf(vp[(size_t)j * S_K]);
#pragma unroll
            for (int mt = 0; mt < 4; ++mt)
                acc[mt][nt] = __builtin_amdgcn_mfma_f32_16x16x32_bf16(
                    af[mt], bvec.b, acc[mt][nt], 0, 0, 0);
        }
    }

    // ---- epilogue: C/D layout col=lane&15, row=quad*4+reg; fp32 out ----
    float* ob = out + base;
#pragma unroll
    for (int mt = 0; mt < 4; ++mt)
#pragma unroll
        for (int nt = 0; nt < 4; ++nt)
#pragma unroll
            for (int reg = 0; reg < 4; ++reg) {
                int m = mt * 16 + quad * 4 + reg;
                int d = dbase + nt * 16 + l15;
                size_t off = (size_t)m * S_K + d;
                float v = acc[mt][nt][reg];
                if (ACCUM) v += ob[off];
                ob[off] = v;
            }
}

extern "C" void kernel_launch(void* const* d_in, const int* in_sizes, int n_in,
                              void* d_out, int out_size, void* d_ws, size_t ws_size,
                              hipStream_t stream) {
    // inputs (fp32): 0=x (UNUSED), 1=attentionXFull, 2=attentionYFull,
    //                3=valueFull, 4=shift, 5=bias
    const float* attX = (const float*)d_in[1];
    const float* attY = (const float*)d_in[2];
    const float* V    = (const float*)d_in[3];
    const float* shp  = (const float*)d_in[4];
    const float* bip  = (const float*)d_in[5];
    float* out = (float*)d_out;

    dim3 blk(256);
    dim3 grid(16 * 64 * 2);  // (b, i, dhalf)
    // X pass: per (b,r) GEMM, writes out
    gauss_gemm<32768, 512, false><<<grid, blk, 0, stream>>>(attX, V, out, shp, bip);
    // Y pass: per (b,c) GEMM, accumulates into out
    gauss_gemm<512, 32768, true><<<grid, blk, 0, stream>>>(attY, V, out, shp, bip);
}

// Round 3
// 414.535 us; speedup vs baseline: 1.0747x; 1.0747x over previous
//
#include <hip/hip_runtime.h>
#include <stdint.h>

// GaussianTrans: out[b,r,c,d] = sum_h sig(disX[c,h]+attX[b,r,c,h]) * V[b,r,h,d]
//                             + sum_w sig(disY[r,w]+attY[b,c,r,w]) * V[b,w,c,d]
// B=16, H=W=64, D=512. fp32 I/O; bf16 MFMA, fp32 accum (absmax 0.0625 vs 0.21 thr).
// R3: coalesced float4 V loads + LDS transpose (was: 64 scalar gathers/lane,
// latency-bound at 24% HBM). 4096 blocks/dispatch (d-quarter tiles).

typedef __attribute__((ext_vector_type(8))) __bf16 bf16x8;
typedef __attribute__((ext_vector_type(8))) short short8;
typedef __attribute__((ext_vector_type(4))) float f32x4;
typedef __attribute__((ext_vector_type(4))) unsigned int uint4v;

union U8 { short8 s; bf16x8 b; unsigned short u[8]; uint4v q; };

__device__ __forceinline__ unsigned short f2bf(float f) {
    union { float f; unsigned int i; } v; v.f = f;
    return (unsigned short)((v.i + 0x7fffu + ((v.i >> 16) & 1u)) >> 16);  // RNE
}
__device__ __forceinline__ float fsigmoid(float x) {
    float e = __builtin_amdgcn_exp2f(-1.44269504f * x);   // exp(-x)
    return __builtin_amdgcn_rcpf(1.0f + e);
}

// One (b, i, dq) tile: M=64 (m), N=128 (d quarter), K=64 (k).
//   A[m][k] = sigmoid(-(shift*(k-m)^2 + bias) + att[(b*64+i)*4096 + m*64 + k])
//   B[k][d] = V[b*2097152 + i*S_I + k*S_K + dstart + d]
//   out at   b*2097152 + i*S_I + m*S_K + dstart + d   (ACCUM: read-add-write)
// X-pass: i=r, S_I=32768, S_K=512.  Y-pass: i=c, S_I=512, S_K=32768.
template <int S_I, int S_K, bool ACCUM>
__global__ __launch_bounds__(256)
void gauss_gemm(const float* __restrict__ att,
                const float* __restrict__ V,
                float* __restrict__ out,
                const float* __restrict__ shiftp,
                const float* __restrict__ biasp) {
    __shared__ unsigned short S[4096];        // sigmoid(A) bf16, frag order [q8][m][j]
    __shared__ unsigned short VT[128 * 66];   // V-tile bf16, [dloc][h], stride 66

    const int bid    = blockIdx.x;
    const int dq     = bid & 3;
    const int i      = (bid >> 2) & 63;
    const int b      = bid >> 8;
    const int t      = threadIdx.x;
    const int dstart = dq * 128;

    const float shift = shiftp[0];
    const float bias  = biasp[0];

    const size_t base = (size_t)b * 2097152 + (size_t)i * S_I;

    // ---- stage A = sigmoid(dis + att) into LDS as bf16, frag-ready ----
    const float* ab = att + (size_t)(b * 64 + i) * 4096;  // [m][k]
#pragma unroll
    for (int chunk = 0; chunk < 2; ++chunk) {
        int flat = t + chunk * 256;          // 0..511 over [q(8)][m(64)]
        int q = flat >> 6, m = flat & 63;
        const float* ap = ab + m * 64 + q * 8;
        f32x4 av0 = *(const f32x4*)(ap);
        f32x4 av1 = *(const f32x4*)(ap + 4);
        U8 res;
#pragma unroll
        for (int j = 0; j < 8; ++j) {
            float a    = (j < 4) ? av0[j & 3] : av1[j & 3];
            float diff = (float)(q * 8 + j - m);            // (k - m)
            float dis  = -(shift * diff * diff + bias);
            res.u[j]   = f2bf(fsigmoid(dis + a));
        }
        *(short8*)(&S[flat * 8]) = res.s;
    }

    // ---- stage V-tile [h=64][dloc=128] -> LDS transposed [dloc][h] bf16 ----
    {
        const float* vb = V + base + dstart;
        const int d4 = t & 31;        // float4 column: dloc = 4*d4 (512B/row coalesced)
        const int h0 = t >> 5;        // 0..7
#pragma unroll
        for (int it = 0; it < 8; ++it) {
            const int h = h0 + it * 8;
            f32x4 v = *(const f32x4*)(vb + (size_t)h * S_K + 4 * d4);
#pragma unroll
            for (int u = 0; u < 4; ++u)
                VT[(4 * d4 + u) * 66 + h] = f2bf(v[u]);
        }
    }
    __syncthreads();

    const int lane = t & 63, wid = t >> 6;
    const int l15 = lane & 15, quad = lane >> 4;

    f32x4 acc[4][2];
#pragma unroll
    for (int mt = 0; mt < 4; ++mt)
#pragma unroll
        for (int nt = 0; nt < 2; ++nt) acc[mt][nt] = (f32x4)0.0f;

#pragma unroll
    for (int ks = 0; ks < 2; ++ks) {
        bf16x8 af[4];
#pragma unroll
        for (int mt = 0; mt < 4; ++mt) {
            U8 a;
            a.s = *(const short8*)(&S[((ks * 4 + quad) * 64 + mt * 16 + l15) * 8]);
            af[mt] = a.b;
        }
        const int h = ks * 32 + quad * 8;
#pragma unroll
        for (int nt = 0; nt < 2; ++nt) {
            const int dloc = wid * 32 + nt * 16 + l15;
            const unsigned short* vp = &VT[dloc * 66 + h];
            U8 bvec;
            uint4v qv;
#pragma unroll
            for (int u = 0; u < 4; ++u) qv[u] = *(const unsigned int*)(vp + 2 * u);
            bvec.q = qv;
#pragma unroll
            for (int mt = 0; mt < 4; ++mt)
                acc[mt][nt] = __builtin_amdgcn_mfma_f32_16x16x32_bf16(
                    af[mt], bvec.b, acc[mt][nt], 0, 0, 0);
        }
    }

    // ---- epilogue: C/D layout col=lane&15, row=quad*4+reg; fp32 out ----
    float* ob = out + base + dstart;
#pragma unroll
    for (int mt = 0; mt < 4; ++mt)
#pragma unroll
        for (int nt = 0; nt < 2; ++nt)
#pragma unroll
            for (int reg = 0; reg < 4; ++reg) {
                int m = mt * 16 + quad * 4 + reg;
                int d = wid * 32 + nt * 16 + l15;
                size_t off = (size_t)m * S_K + d;
                float v = acc[mt][nt][reg];
                if (ACCUM) v += ob[off];
                ob[off] = v;
            }
}

extern "C" void kernel_launch(void* const* d_in, const int* in_sizes, int n_in,
                              void* d_out, int out_size, void* d_ws, size_t ws_size,
                              hipStream_t stream) {
    // inputs (fp32): 0=x (UNUSED), 1=attentionXFull, 2=attentionYFull,
    //                3=valueFull, 4=shift, 5=bias
    const float* attX = (const float*)d_in[1];
    const float* attY = (const float*)d_in[2];
    const float* V    = (const float*)d_in[3];
    const float* shp  = (const float*)d_in[4];
    const float* bip  = (const float*)d_in[5];
    float* out = (float*)d_out;

    dim3 blk(256);
    dim3 grid(16 * 64 * 4);  // (b, i, dquarter)
    // X pass: per (b,r) GEMM, writes out
    gauss_gemm<32768, 512, false><<<grid, blk, 0, stream>>>(attX, V, out, shp, bip);
    // Y pass: per (b,c) GEMM, accumulates into out
    gauss_gemm<512, 32768, true><<<grid, blk, 0, stream>>>(attY, V, out, shp, bip);
}